// Round 7
// baseline (314.577 us; speedup 1.0000x reference)
//
#include <hip/hip_runtime.h>
#include <hip/hip_bf16.h>
#include <math.h>

// Problem constants (fixed by reference setup_inputs)
constexpr int NROWS = 8192;   // B
constexpr int HDIM  = 256;    // H (= K of the GEMM)
constexpr int N2    = 16384;  // 2*B rows of Z
constexpr int BM    = 128;    // tile M = tile N
constexpr int NTILE = N2 / BM;        // 128 tile-rows
constexpr int NBLK  = NTILE * (NTILE + 1) / 2;  // 8256 upper-tri tiles

// sqrt(2 * log2(e)): Z pre-scaled so Zs_i.Zs_j = 2*log2(e)*cos and
// exp2(acc) == exp(sim/tau), tau = 0.5
constexpr float PRESCALE = 1.69864357f;

typedef __attribute__((ext_vector_type(4))) float floatx4;
typedef __attribute__((ext_vector_type(8))) short shortx8; // 8 bf16 = 4 VGPRs

// ---------------------------------------------------------------------------
// Kernel 1: wave-per-row L2-normalize -> bf16 Z (pre-scaled); pos = cos(x,y).
// Also zeroes rowsum and out (stream-ordered before consumers).
// ---------------------------------------------------------------------------
__global__ __launch_bounds__(256) void normalize_kernel(
    const float* __restrict__ x, const float* __restrict__ y,
    __hip_bfloat16* __restrict__ Z, float* __restrict__ pos,
    float* __restrict__ rowsum, float* __restrict__ out)
{
    const int wave = threadIdx.x >> 6, lane = threadIdx.x & 63;
    const int row  = blockIdx.x * 4 + wave;           // grid 2048 -> 8192 rows

    const float4 xv = ((const float4*)x)[row * 64 + lane];
    const float4 yv = ((const float4*)y)[row * 64 + lane];

    float sx  = xv.x*xv.x + xv.y*xv.y + xv.z*xv.z + xv.w*xv.w;
    float sy  = yv.x*yv.x + yv.y*yv.y + yv.z*yv.z + yv.w*yv.w;
    float sxy = xv.x*yv.x + xv.y*yv.y + xv.z*yv.z + xv.w*yv.w;
    #pragma unroll
    for (int m = 1; m < 64; m <<= 1) {
        sx  += __shfl_xor(sx,  m);
        sy  += __shfl_xor(sy,  m);
        sxy += __shfl_xor(sxy, m);
    }
    const float rxn = rsqrtf(sx), ryn = rsqrtf(sy);
    const float rx = rxn * PRESCALE, ry = ryn * PRESCALE;

    union { ushort4 u; __hip_bfloat16 h[4]; } zx, zy;
    zx.h[0] = __float2bfloat16(xv.x * rx); zx.h[1] = __float2bfloat16(xv.y * rx);
    zx.h[2] = __float2bfloat16(xv.z * rx); zx.h[3] = __float2bfloat16(xv.w * rx);
    zy.h[0] = __float2bfloat16(yv.x * ry); zy.h[1] = __float2bfloat16(yv.y * ry);
    zy.h[2] = __float2bfloat16(yv.z * ry); zy.h[3] = __float2bfloat16(yv.w * ry);
    ((ushort4*)Z)[row * 64 + lane]             = zx.u;
    ((ushort4*)Z)[(row + NROWS) * 64 + lane]   = zy.u;

    if (lane == 0) {
        const float p = sxy * rxn * ryn;
        pos[row]         = p;
        pos[row + NROWS] = p;
    }
    const int gt = blockIdx.x * 256 + threadIdx.x;
    if (gt < N2) rowsum[gt] = 0.f;
    if (gt == 0) out[0] = 0.f;
}

// ---------------------------------------------------------------------------
// Kernel 2: upper-triangle tiled Z·Z^T, fused exp2 + row/col sums.
// DIRECT-FROM-CACHE GEMM: no LDS staging, no K-loop barriers. Both MFMA
// operand layouts (A[m=lane&15][k=g*8+j], B[n=lane&15][k=g*8+j]) are
// "16 consecutive rows x 16B contiguous" — loadable straight from row-major
// Z with global_load_dwordx4. The hot k-slice (16 KB/block) lives in L1/L2;
// reuse across waves/blocks is served by cache instead of LDS. Software
// pipeline: load k-step s+1's 8 fragments while MFMAing step s. Waves run
// fully independently (R6 showed the 2-barrier-per-chunk LDS pipeline stalls
// both pipes at ~25% — prefetch distance can't cover L2 latency in lockstep).
// NO device-scope fences (R5: per-block threadfence+acq-rel collapses L2).
// ---------------------------------------------------------------------------
__global__ __launch_bounds__(256, 3) void simgemm_kernel(
    const __hip_bfloat16* __restrict__ Z, float* __restrict__ rowsum)
{
    // linear -> (bi, bj) upper-triangle mapping; cum(bi) = bi*(257-bi)/2
    const int b = blockIdx.x;
    int bi = (int)((257.0f - sqrtf(66049.0f - 8.0f * (float)b)) * 0.5f);
    int cum = bi * (257 - bi) / 2;
    if (b < cum)      { bi--; cum = bi * (257 - bi) / 2; }
    else { const int cn = (bi + 1) * (256 - bi) / 2;
           if (b >= cn) { bi++; cum = cn; } }
    const int bj = bi + (b - cum);
    const bool diag = (bi == bj);

    __shared__ float rs[BM];
    __shared__ float cs[BM];

    const int tid  = threadIdx.x;
    const int wave = tid >> 6;
    const int lane = tid & 63;
    const int wm   = wave & 1;            // wave row (0..1)
    const int wn   = wave >> 1;           // wave col (0..1)
    const int g    = lane >> 4;           // quad  (0..3)
    const int m15  = lane & 15;

    if (tid < BM) { rs[tid] = 0.f; cs[tid] = 0.f; }
    __syncthreads();   // rs/cs ready before epilogue atomics (only barrier)

    // per-lane fragment base pointers; fragment (f, s) is at
    // base + f*16*HDIM + s*32  (constants fold to addr-reg + imm offsets)
    const __hip_bfloat16* pA = Z + (size_t)(bi * BM + wm * 64 + m15) * HDIM + g * 8;
    const __hip_bfloat16* pB = Z + (size_t)(bj * BM + wn * 64 + m15) * HDIM + g * 8;

    floatx4 acc[4][4] = {};
    shortx8 afr[2][4], bfr[2][4];

    #pragma unroll
    for (int f = 0; f < 4; ++f) {
        afr[0][f] = *(const shortx8*)(pA + f * 16 * HDIM);
        bfr[0][f] = *(const shortx8*)(pB + f * 16 * HDIM);
    }

    #pragma unroll
    for (int s = 0; s < HDIM / 32; ++s) {          // 8 k-steps of 32
        const int cur = s & 1;
        if (s + 1 < HDIM / 32) {
            #pragma unroll
            for (int f = 0; f < 4; ++f) {
                afr[cur ^ 1][f] = *(const shortx8*)(pA + f * 16 * HDIM + (s + 1) * 32);
                bfr[cur ^ 1][f] = *(const shortx8*)(pB + f * 16 * HDIM + (s + 1) * 32);
            }
        }
        #pragma unroll
        for (int fm = 0; fm < 4; ++fm)
            #pragma unroll
            for (int fn = 0; fn < 4; ++fn)
                acc[fm][fn] = __builtin_amdgcn_mfma_f32_16x16x32_bf16(
                    afr[cur][fm], bfr[cur][fn], acc[fm][fn], 0, 0, 0);
    }

    // ---- epilogue: e = exp2(acc) (== exp(sim/tau)), reduce rows & cols ----
    float rp[4][4] = {{0.f}};  // [fm][reg] partial row sums
    float cp[4]    = {0.f};    // [fn]      partial col sums

    if (!diag) {
        #pragma unroll
        for (int fm = 0; fm < 4; ++fm)
            #pragma unroll
            for (int fn = 0; fn < 4; ++fn) {
                const floatx4 a = acc[fm][fn];
                #pragma unroll
                for (int q = 0; q < 4; ++q) {
                    const float e = __builtin_amdgcn_exp2f(a[q]);
                    rp[fm][q] += e;
                    cp[fn]    += e;
                }
            }
    } else {
        #pragma unroll
        for (int fm = 0; fm < 4; ++fm)
            #pragma unroll
            for (int fn = 0; fn < 4; ++fn) {
                const floatx4 a = acc[fm][fn];
                const int cl = wn * 64 + fn * 16 + m15;
                #pragma unroll
                for (int q = 0; q < 4; ++q) {
                    const int rl = wm * 64 + fm * 16 + g * 4 + q;
                    float e = __builtin_amdgcn_exp2f(a[q]);
                    if (cl <= rl) e = 0.f;   // strictly-upper only
                    rp[fm][q] += e;
                    cp[fn]    += e;
                }
            }
    }

    // row sums: reduce across the 16 lanes sharing a quad (same rows)
    #pragma unroll
    for (int mask = 1; mask < 16; mask <<= 1)
        #pragma unroll
        for (int fm = 0; fm < 4; ++fm)
            #pragma unroll
            for (int q = 0; q < 4; ++q)
                rp[fm][q] += __shfl_xor(rp[fm][q], mask);
    if (m15 == 0) {
        #pragma unroll
        for (int fm = 0; fm < 4; ++fm)
            #pragma unroll
            for (int q = 0; q < 4; ++q)
                atomicAdd(&rs[wm * 64 + fm * 16 + g * 4 + q], rp[fm][q]);
    }

    // col sums: reduce across quads (same cols)
    #pragma unroll
    for (int mask = 16; mask < 64; mask <<= 1)
        #pragma unroll
        for (int fn = 0; fn < 4; ++fn)
            cp[fn] += __shfl_xor(cp[fn], mask);
    if (g == 0) {
        #pragma unroll
        for (int fn = 0; fn < 4; ++fn)
            atomicAdd(&cs[wn * 64 + fn * 16 + m15], cp[fn]);
    }

    __syncthreads();
    if (tid < BM) {
        atomicAdd(&rowsum[(size_t)bi * BM + tid], rs[tid]);
        atomicAdd(&rowsum[(size_t)bj * BM + tid], cs[tid]);
    }
}

// ---------------------------------------------------------------------------
// Kernel 3: loss = mean( log(rowsum_i) - 2*pos_i ), 16 blocks + atomic.
// out[0] zeroed by normalize_kernel (stream-ordered).
// ---------------------------------------------------------------------------
__global__ __launch_bounds__(1024) void finalize_kernel(
    const float* __restrict__ rowsum, const float* __restrict__ pos,
    float* __restrict__ out)
{
    const int i = threadIdx.x + blockIdx.x * 1024;
    float s = logf(rowsum[i]) - 2.0f * pos[i];
    #pragma unroll
    for (int off = 32; off; off >>= 1) s += __shfl_down(s, off);
    __shared__ float sh[16];
    const int lt = threadIdx.x;
    if ((lt & 63) == 0) sh[lt >> 6] = s;
    __syncthreads();
    if (lt == 0) {
        float tot = 0.f;
        #pragma unroll
        for (int w = 0; w < 16; ++w) tot += sh[w];
        atomicAdd(out, tot / (float)N2);
    }
}

// ---------------------------------------------------------------------------
extern "C" void kernel_launch(void* const* d_in, const int* in_sizes, int n_in,
                              void* d_out, int out_size, void* d_ws, size_t ws_size,
                              hipStream_t stream)
{
    const float* x = (const float*)d_in[0];
    const float* y = (const float*)d_in[1];

    // workspace: Z bf16 [16384*256] (8 MB) | rowsum f32 [16384] | pos f32 [16384]
    __hip_bfloat16* Z = (__hip_bfloat16*)d_ws;
    float* rowsum = (float*)((char*)d_ws + (size_t)N2 * HDIM * sizeof(__hip_bfloat16));
    float* pos    = rowsum + N2;

    normalize_kernel<<<NROWS / 4, 256, 0, stream>>>(x, y, Z, pos, rowsum, (float*)d_out);
    simgemm_kernel<<<NBLK, 256, 0, stream>>>(Z, rowsum);
    finalize_kernel<<<N2 / 1024, 1024, 0, stream>>>(rowsum, pos, (float*)d_out);
}

// Round 8
// 176.347 us; speedup vs baseline: 1.7839x; 1.7839x over previous
//
#include <hip/hip_runtime.h>
#include <hip/hip_bf16.h>
#include <math.h>

// Problem constants (fixed by reference setup_inputs)
constexpr int NROWS = 8192;   // B
constexpr int HDIM  = 256;    // H (= K of the GEMM)
constexpr int N2    = 16384;  // 2*B rows of Z
constexpr int BM    = 128;    // tile M = tile N
constexpr int BK    = 32;     // K chunk staged per round (8 chunks)
constexpr int NCHUNK = HDIM / BK;     // 8
constexpr int NTILE = N2 / BM;        // 128 tile-rows
constexpr int NBLK  = NTILE * (NTILE + 1) / 2;  // 8256 upper-tri tiles

// sqrt(2 * log2(e)): Z pre-scaled so Zs_i.Zs_j = 2*log2(e)*cos and
// exp2(acc) == exp(sim/tau), tau = 0.5
constexpr float PRESCALE = 1.69864357f;

typedef __attribute__((ext_vector_type(4))) float floatx4;
typedef __attribute__((ext_vector_type(8))) short shortx8; // 8 bf16 = 4 VGPRs

__device__ __forceinline__ void async_copy16(const void* gptr, void* lptr) {
    __builtin_amdgcn_global_load_lds(
        (const __attribute__((address_space(1))) unsigned int*)gptr,
        (__attribute__((address_space(3))) unsigned int*)lptr, 16, 0, 0);
}

// s_waitcnt immediates (gfx9: vm[3:0], exp[6:4], lgkm[11:8], vm-hi[15:14])
#define WAIT_VM8()   __builtin_amdgcn_s_waitcnt(0x0F78)  // vmcnt(8)
#define WAIT_VM4()   __builtin_amdgcn_s_waitcnt(0x0F74)  // vmcnt(4)
#define WAIT_VM0()   __builtin_amdgcn_s_waitcnt(0x0F70)  // vmcnt(0)
#define WAIT_LGKM0() __builtin_amdgcn_s_waitcnt(0xC07F)  // lgkmcnt(0)
#define MEMFENCE()   __asm__ __volatile__("" ::: "memory")
#define RAW_BARRIER() do { MEMFENCE(); __builtin_amdgcn_s_barrier(); MEMFENCE(); } while (0)

// ---------------------------------------------------------------------------
// Kernel 1: wave-per-row L2-normalize -> bf16 Z (pre-scaled); pos = cos(x,y).
// Also zeroes rowsum and out (stream-ordered before consumers).
// ---------------------------------------------------------------------------
__global__ __launch_bounds__(256) void normalize_kernel(
    const float* __restrict__ x, const float* __restrict__ y,
    __hip_bfloat16* __restrict__ Z, float* __restrict__ pos,
    float* __restrict__ rowsum, float* __restrict__ out)
{
    const int wave = threadIdx.x >> 6, lane = threadIdx.x & 63;
    const int row  = blockIdx.x * 4 + wave;           // grid 2048 -> 8192 rows

    const float4 xv = ((const float4*)x)[row * 64 + lane];
    const float4 yv = ((const float4*)y)[row * 64 + lane];

    float sx  = xv.x*xv.x + xv.y*xv.y + xv.z*xv.z + xv.w*xv.w;
    float sy  = yv.x*yv.x + yv.y*yv.y + yv.z*yv.z + yv.w*yv.w;
    float sxy = xv.x*yv.x + xv.y*yv.y + xv.z*yv.z + xv.w*yv.w;
    #pragma unroll
    for (int m = 1; m < 64; m <<= 1) {
        sx  += __shfl_xor(sx,  m);
        sy  += __shfl_xor(sy,  m);
        sxy += __shfl_xor(sxy, m);
    }
    const float rxn = rsqrtf(sx), ryn = rsqrtf(sy);
    const float rx = rxn * PRESCALE, ry = ryn * PRESCALE;

    union { ushort4 u; __hip_bfloat16 h[4]; } zx, zy;
    zx.h[0] = __float2bfloat16(xv.x * rx); zx.h[1] = __float2bfloat16(xv.y * rx);
    zx.h[2] = __float2bfloat16(xv.z * rx); zx.h[3] = __float2bfloat16(xv.w * rx);
    zy.h[0] = __float2bfloat16(yv.x * ry); zy.h[1] = __float2bfloat16(yv.y * ry);
    zy.h[2] = __float2bfloat16(yv.z * ry); zy.h[3] = __float2bfloat16(yv.w * ry);
    ((ushort4*)Z)[row * 64 + lane]             = zx.u;
    ((ushort4*)Z)[(row + NROWS) * 64 + lane]   = zy.u;

    if (lane == 0) {
        const float p = sxy * rxn * ryn;
        pos[row]         = p;
        pos[row + NROWS] = p;
    }
    const int gt = blockIdx.x * 256 + threadIdx.x;
    if (gt < N2) rowsum[gt] = 0.f;
    if (gt == 0) out[0] = 0.f;
}

// ---------------------------------------------------------------------------
// Kernel 2: upper-triangle tiled Z·Z^T, fused exp2 + row/col sums.
// R6 structure (best: 126.8us) + two changes:
//  (1) TRIPLE-buffered BK=32 staging, prefetch depth 2: body s stages chunk
//      s+2, then waits vmcnt(8) (chunk s's 4 loads issued TWO bodies ago ->
//      ~500cyc slack, covers L2-miss/L3 latency). LDS 49KB -> 3 blocks/CU.
//  (2) XCD-locality mapping: 8 row-groups of 16 tiles (1MB). XCD k
//      (= blockIdx%8, round-robin heuristic) gets diag pair k (136 tiles)
//      + 7 half-pairs (128 tiles, 1.5MB footprint) = exactly 1032 blocks.
//      Working set per XCD at any time <= 2MB -> L2-resident.
// NO device-scope fences (R5: collapses L2). No direct-from-global frags
// (R7: 16-segment scatter saturates TA).
// ---------------------------------------------------------------------------
__global__ __launch_bounds__(256, 3) void simgemm_kernel(
    const __hip_bfloat16* __restrict__ Z, float* __restrict__ rowsum)
{
    // ---- XCD-local block -> (bi,bj) mapping (bijection onto upper tri) ----
    const int b = blockIdx.x;
    const int k = b & 7;        // XCD under round-robin dispatch heuristic
    const int m = b >> 3;       // 0..1031 local rank within XCD
    int bi, bj;
    if (m < 136) {
        // diagonal group-pair k: 16x16 upper triangle, cum(t) = t*(33-t)/2
        int ti = (int)((33.0f - sqrtf(1089.0f - 8.0f * (float)m)) * 0.5f);
        if (m < ti * (33 - ti) / 2) ti--;
        else if (m >= (ti + 1) * (32 - ti) / 2) ti++;
        const int tj = ti + (m - ti * (33 - ti) / 2);
        bi = k * 16 + ti;
        bj = k * 16 + tj;
    } else {
        const int m2 = m - 136;          // 0..895
        const int hh = m2 >> 7;          // 0..6  (which of my 7 halves)
        const int r  = m2 & 127;         // 0..127 within half (8x16 tiles)
        const int h  = hh * 8 + k;       // 0..55 global half index
        const int q  = h >> 1;           // 0..27 off-diag group pair
        const int sub = h & 1;
        // pair q -> (gi,gj), gi<gj, cum(gi) = gi*(15-gi)/2
        int gi = 0;
        #pragma unroll
        for (int t = 6; t > 0; --t)
            if (q >= t * (15 - t) / 2) { gi = t; break; }
        const int gj = gi + 1 + (q - gi * (15 - gi) / 2);
        bi = gi * 16 + sub * 8 + (r >> 4);
        bj = gj * 16 + (r & 15);
    }
    const bool diag = (bi == bj);

    // LDS: 3 buffers x (tA 8KB + tB 8KB) = 48KB, + rs/cs 1KB
    __shared__ alignas(16) __hip_bfloat16 tiles[6 * BM * BK];  // 48 KB
    __shared__ float rs[BM];
    __shared__ float cs[BM];
    // buffer B: tA at tiles + B*8192 elem? (elements): stride 2*BM*BK = 8192
    __hip_bfloat16* tA = tiles;                  // + buf * 2*BM*BK
    __hip_bfloat16* tB = tiles + BM * BK;        // + buf * 2*BM*BK

    const int tid  = threadIdx.x;
    const int wave = tid >> 6;
    const int lane = tid & 63;
    const int wm   = wave & 1;            // wave row (0..1)
    const int wn   = wave >> 1;           // wave col (0..1)
    const int g    = lane >> 4;           // quad  (0..3)
    const int m15  = lane & 15;

    if (tid < BM) { rs[tid] = 0.f; cs[tid] = 0.f; }

    // ---- staging addresses (computed once) ----
    // lane l covers LDS row rr = wave*32 + t*16 + (l>>2), lds chunk l&3;
    // swizzled source chunk = (l&3) ^ ((l>>3)&3)   [R6-validated, 0 conflicts]
    const int st_r0  = wave * 32 + (lane >> 2);            // t=0 row
    const int st_c   = (lane & 3) ^ ((lane >> 3) & 3);     // source chunk
    const __hip_bfloat16* gA0 = Z + (size_t)(bi * BM + st_r0) * HDIM + st_c * 8;
    const __hip_bfloat16* gA1 = gA0 + 16 * HDIM;           // t=1 rows
    const __hip_bfloat16* gB0 = Z + (size_t)(bj * BM + st_r0) * HDIM + st_c * 8;
    const __hip_bfloat16* gB1 = gB0 + 16 * HDIM;
    // wave-uniform LDS bases (lane scatter is +l*16B)
    __hip_bfloat16* lA0 = tA + (wave * 32) * BK;
    __hip_bfloat16* lA1 = tA + (wave * 32 + 16) * BK;
    __hip_bfloat16* lB0 = tB + (wave * 32) * BK;
    __hip_bfloat16* lB1 = tB + (wave * 32 + 16) * BK;

    // ---- fragment read addresses (all offsets immediates) ----
    const int sw = g ^ ((m15 >> 1) & 3);
    const __hip_bfloat16* rA = tA + (wm * 64 + m15) * BK + sw * 8;
    const __hip_bfloat16* rB = tB + (wn * 64 + m15) * BK + sw * 8;

    floatx4 acc[4][4] = {};

    // chunk ck -> buffer ck%3; global offset ck*BK folds to imm
    #define STAGE(ck)  do {                                                  \
        const int _o = ((ck) % 3) * 2 * BM * BK;                             \
        async_copy16(gA0 + (ck) * BK, lA0 + _o);                             \
        async_copy16(gA1 + (ck) * BK, lA1 + _o);                             \
        async_copy16(gB0 + (ck) * BK, lB0 + _o);                             \
        async_copy16(gB1 + (ck) * BK, lB1 + _o);                             \
    } while (0)

    STAGE(0);
    STAGE(1);

    #pragma unroll
    for (int s = 0; s < NCHUNK; ++s) {
        if (s + 2 < NCHUNK)      { STAGE(s + 2); WAIT_VM8(); }
        else if (s + 1 < NCHUNK) { WAIT_VM4(); }
        else                     { WAIT_VM0(); }
        RAW_BARRIER();   // chunk s landed in buffer s%3 (all waves)

        const int bo = (s % 3) * 2 * BM * BK;
        shortx8 af[4], bfr[4];
        #pragma unroll
        for (int f = 0; f < 4; ++f) {
            af[f]  = *(const shortx8*)(rA + bo + f * 16 * BK);
            bfr[f] = *(const shortx8*)(rB + bo + f * 16 * BK);
        }
        #pragma unroll
        for (int fm = 0; fm < 4; ++fm)
            #pragma unroll
            for (int fn = 0; fn < 4; ++fn)
                acc[fm][fn] = __builtin_amdgcn_mfma_f32_16x16x32_bf16(
                    af[fm], bfr[fn], acc[fm][fn], 0, 0, 0);

        WAIT_LGKM0();    // this buffer's ds_reads complete
        RAW_BARRIER();   // WAR: before buffer s%3 is restaged (body s+1's STAGE(s+3))
    }
    #undef STAGE

    // ---- epilogue: e = exp2(acc) (== exp(sim/tau)), reduce rows & cols ----
    float rp[4][4] = {{0.f}};  // [fm][reg] partial row sums
    float cp[4]    = {0.f};    // [fn]      partial col sums

    if (!diag) {
        #pragma unroll
        for (int fm = 0; fm < 4; ++fm)
            #pragma unroll
            for (int fn = 0; fn < 4; ++fn) {
                const floatx4 a = acc[fm][fn];
                #pragma unroll
                for (int q = 0; q < 4; ++q) {
                    const float e = __builtin_amdgcn_exp2f(a[q]);
                    rp[fm][q] += e;
                    cp[fn]    += e;
                }
            }
    } else {
        #pragma unroll
        for (int fm = 0; fm < 4; ++fm)
            #pragma unroll
            for (int fn = 0; fn < 4; ++fn) {
                const floatx4 a = acc[fm][fn];
                const int cl = wn * 64 + fn * 16 + m15;
                #pragma unroll
                for (int q = 0; q < 4; ++q) {
                    const int rl = wm * 64 + fm * 16 + g * 4 + q;
                    float e = __builtin_amdgcn_exp2f(a[q]);
                    if (cl <= rl) e = 0.f;   // strictly-upper only
                    rp[fm][q] += e;
                    cp[fn]    += e;
                }
            }
    }

    // row sums: reduce across the 16 lanes sharing a quad (same rows)
    #pragma unroll
    for (int mask = 1; mask < 16; mask <<= 1)
        #pragma unroll
        for (int fm = 0; fm < 4; ++fm)
            #pragma unroll
            for (int q = 0; q < 4; ++q)
                rp[fm][q] += __shfl_xor(rp[fm][q], mask);
    if (m15 == 0) {
        #pragma unroll
        for (int fm = 0; fm < 4; ++fm)
            #pragma unroll
            for (int q = 0; q < 4; ++q)
                atomicAdd(&rs[wm * 64 + fm * 16 + g * 4 + q], rp[fm][q]);
    }

    // col sums: reduce across quads (same cols)
    #pragma unroll
    for (int mask = 16; mask < 64; mask <<= 1)
        #pragma unroll
        for (int fn = 0; fn < 4; ++fn)
            cp[fn] += __shfl_xor(cp[fn], mask);
    if (g == 0) {
        #pragma unroll
        for (int fn = 0; fn < 4; ++fn)
            atomicAdd(&cs[wn * 64 + fn * 16 + m15], cp[fn]);
    }

    __syncthreads();
    if (tid < BM) {
        atomicAdd(&rowsum[(size_t)bi * BM + tid], rs[tid]);
        atomicAdd(&rowsum[(size_t)bj * BM + tid], cs[tid]);
    }
}

// ---------------------------------------------------------------------------
// Kernel 3: loss = mean( log(rowsum_i) - 2*pos_i ), 16 blocks + atomic.
// out[0] zeroed by normalize_kernel (stream-ordered).
// ---------------------------------------------------------------------------
__global__ __launch_bounds__(1024) void finalize_kernel(
    const float* __restrict__ rowsum, const float* __restrict__ pos,
    float* __restrict__ out)
{
    const int i = threadIdx.x + blockIdx.x * 1024;
    float s = logf(rowsum[i]) - 2.0f * pos[i];
    #pragma unroll
    for (int off = 32; off; off >>= 1) s += __shfl_down(s, off);
    __shared__ float sh[16];
    const int lt = threadIdx.x;
    if ((lt & 63) == 0) sh[lt >> 6] = s;
    __syncthreads();
    if (lt == 0) {
        float tot = 0.f;
        #pragma unroll
        for (int w = 0; w < 16; ++w) tot += sh[w];
        atomicAdd(out, tot / (float)N2);
    }
}

// ---------------------------------------------------------------------------
extern "C" void kernel_launch(void* const* d_in, const int* in_sizes, int n_in,
                              void* d_out, int out_size, void* d_ws, size_t ws_size,
                              hipStream_t stream)
{
    const float* x = (const float*)d_in[0];
    const float* y = (const float*)d_in[1];

    // workspace: Z bf16 [16384*256] (8 MB) | rowsum f32 [16384] | pos f32 [16384]
    __hip_bfloat16* Z = (__hip_bfloat16*)d_ws;
    float* rowsum = (float*)((char*)d_ws + (size_t)N2 * HDIM * sizeof(__hip_bfloat16));
    float* pos    = rowsum + N2;

    normalize_kernel<<<NROWS / 4, 256, 0, stream>>>(x, y, Z, pos, rowsum, (float*)d_out);
    simgemm_kernel<<<NBLK, 256, 0, stream>>>(Z, rowsum);
    finalize_kernel<<<N2 / 1024, 1024, 0, stream>>>(rowsum, pos, (float*)d_out);
}

// Round 9
// 158.970 us; speedup vs baseline: 1.9788x; 1.1093x over previous
//
#include <hip/hip_runtime.h>
#include <hip/hip_bf16.h>
#include <math.h>

// Problem constants (fixed by reference setup_inputs)
constexpr int NROWS = 8192;   // B
constexpr int HDIM  = 256;    // H (= K of the GEMM)
constexpr int N2    = 16384;  // 2*B rows of Z
constexpr int BM    = 128;    // tile M = tile N
constexpr int BK    = 32;     // K chunk staged per round (8 chunks)
constexpr int NCHUNK = HDIM / BK;     // 8
constexpr int NTILE = N2 / BM;        // 128 tile-rows
constexpr int NBLK  = NTILE * (NTILE + 1) / 2;  // 8256 upper-tri tiles

// sqrt(2 * log2(e)): Z pre-scaled so Zs_i.Zs_j = 2*log2(e)*cos and
// exp2(acc) == exp(sim/tau), tau = 0.5
constexpr float PRESCALE = 1.69864357f;

typedef __attribute__((ext_vector_type(4))) float floatx4;
typedef __attribute__((ext_vector_type(8))) short shortx8; // 8 bf16 = 4 VGPRs

__device__ __forceinline__ void async_copy16(const void* gptr, void* lptr) {
    __builtin_amdgcn_global_load_lds(
        (const __attribute__((address_space(1))) unsigned int*)gptr,
        (__attribute__((address_space(3))) unsigned int*)lptr, 16, 0, 0);
}

// s_waitcnt immediates (gfx9: vm[3:0], exp[6:4], lgkm[11:8], vm-hi[15:14])
#define WAIT_VM8()   __builtin_amdgcn_s_waitcnt(0x0F78)  // vmcnt(8)
#define WAIT_VM4()   __builtin_amdgcn_s_waitcnt(0x0F74)  // vmcnt(4)
#define WAIT_VM0()   __builtin_amdgcn_s_waitcnt(0x0F70)  // vmcnt(0)
#define WAIT_LGKM0() __builtin_amdgcn_s_waitcnt(0xC07F)  // lgkmcnt(0)
#define MEMFENCE()   __asm__ __volatile__("" ::: "memory")
#define RAW_BARRIER() do { MEMFENCE(); __builtin_amdgcn_s_barrier(); MEMFENCE(); } while (0)

// DPP-based add of a row_shl-moved copy: VALU pipe, NOT the DS pipe.
// (The R8 epilogue's 64 __shfl_xor -> ds_bpermute per wave were ~37% of the
// CU's DS-pipe budget — bigger than the K-loop's ds_reads.)
// row_shl:N ctrl = 0x100+N; bound_ctrl=1 -> OOB lanes read 0.
// After shl 1,2,4,8: lane 0 of each 16-lane row holds the row's total.
#define DPP_ROW_SHL_ADD(v, CTRL) do {                                        \
    union { float f; int i; } _u, _r; _u.f = (v);                            \
    _r.i = __builtin_amdgcn_update_dpp(0, _u.i, (CTRL), 0xF, 0xF, true);     \
    (v) += _r.f; } while (0)

// ---------------------------------------------------------------------------
// Kernel 1: wave-per-row L2-normalize -> bf16 Z (pre-scaled); pos = cos(x,y).
// Also zeroes rowsum and out (stream-ordered before consumers).
// ---------------------------------------------------------------------------
__global__ __launch_bounds__(256) void normalize_kernel(
    const float* __restrict__ x, const float* __restrict__ y,
    __hip_bfloat16* __restrict__ Z, float* __restrict__ pos,
    float* __restrict__ rowsum, float* __restrict__ out)
{
    const int wave = threadIdx.x >> 6, lane = threadIdx.x & 63;
    const int row  = blockIdx.x * 4 + wave;           // grid 2048 -> 8192 rows

    const float4 xv = ((const float4*)x)[row * 64 + lane];
    const float4 yv = ((const float4*)y)[row * 64 + lane];

    float sx  = xv.x*xv.x + xv.y*xv.y + xv.z*xv.z + xv.w*xv.w;
    float sy  = yv.x*yv.x + yv.y*yv.y + yv.z*yv.z + yv.w*yv.w;
    float sxy = xv.x*yv.x + xv.y*yv.y + xv.z*yv.z + xv.w*yv.w;
    #pragma unroll
    for (int m = 1; m < 64; m <<= 1) {
        sx  += __shfl_xor(sx,  m);
        sy  += __shfl_xor(sy,  m);
        sxy += __shfl_xor(sxy, m);
    }
    const float rxn = rsqrtf(sx), ryn = rsqrtf(sy);
    const float rx = rxn * PRESCALE, ry = ryn * PRESCALE;

    union { ushort4 u; __hip_bfloat16 h[4]; } zx, zy;
    zx.h[0] = __float2bfloat16(xv.x * rx); zx.h[1] = __float2bfloat16(xv.y * rx);
    zx.h[2] = __float2bfloat16(xv.z * rx); zx.h[3] = __float2bfloat16(xv.w * rx);
    zy.h[0] = __float2bfloat16(yv.x * ry); zy.h[1] = __float2bfloat16(yv.y * ry);
    zy.h[2] = __float2bfloat16(yv.z * ry); zy.h[3] = __float2bfloat16(yv.w * ry);
    ((ushort4*)Z)[row * 64 + lane]             = zx.u;
    ((ushort4*)Z)[(row + NROWS) * 64 + lane]   = zy.u;

    if (lane == 0) {
        const float p = sxy * rxn * ryn;
        pos[row]         = p;
        pos[row + NROWS] = p;
    }
    const int gt = blockIdx.x * 256 + threadIdx.x;
    if (gt < N2) rowsum[gt] = 0.f;
    if (gt == 0) out[0] = 0.f;
}

// ---------------------------------------------------------------------------
// Kernel 2: upper-triangle tiled Z·Z^T, fused exp2 + row/col sums.
// R8 structure (tbuf BK=32 depth-2 prefetch, XCD-locality mapping) with the
// epilogue row-reduction moved from ds_bpermute (DS pipe) to DPP (VALU pipe).
// NO device-scope fences (R5: collapses L2). No direct-from-global frags
// (R7: 16-segment scatter saturates TA).
// ---------------------------------------------------------------------------
__global__ __launch_bounds__(256, 3) void simgemm_kernel(
    const __hip_bfloat16* __restrict__ Z, float* __restrict__ rowsum)
{
    // ---- XCD-local block -> (bi,bj) mapping (bijection onto upper tri) ----
    const int b = blockIdx.x;
    const int k = b & 7;        // XCD under round-robin dispatch heuristic
    const int m = b >> 3;       // 0..1031 local rank within XCD
    int bi, bj;
    if (m < 136) {
        // diagonal group-pair k: 16x16 upper triangle, cum(t) = t*(33-t)/2
        int ti = (int)((33.0f - sqrtf(1089.0f - 8.0f * (float)m)) * 0.5f);
        if (m < ti * (33 - ti) / 2) ti--;
        else if (m >= (ti + 1) * (32 - ti) / 2) ti++;
        const int tj = ti + (m - ti * (33 - ti) / 2);
        bi = k * 16 + ti;
        bj = k * 16 + tj;
    } else {
        const int m2 = m - 136;          // 0..895
        const int hh = m2 >> 7;          // 0..6  (which of my 7 halves)
        const int r  = m2 & 127;         // 0..127 within half (8x16 tiles)
        const int h  = hh * 8 + k;       // 0..55 global half index
        const int q  = h >> 1;           // 0..27 off-diag group pair
        const int sub = h & 1;
        // pair q -> (gi,gj), gi<gj, cum(gi) = gi*(15-gi)/2
        int gi = 0;
        #pragma unroll
        for (int t = 6; t > 0; --t)
            if (q >= t * (15 - t) / 2) { gi = t; break; }
        const int gj = gi + 1 + (q - gi * (15 - gi) / 2);
        bi = gi * 16 + sub * 8 + (r >> 4);
        bj = gj * 16 + (r & 15);
    }
    const bool diag = (bi == bj);

    // LDS: 3 buffers x (tA 8KB + tB 8KB) = 48KB, + rs/cs 1KB
    __shared__ alignas(16) __hip_bfloat16 tiles[6 * BM * BK];  // 48 KB
    __shared__ float rs[BM];
    __shared__ float cs[BM];
    __hip_bfloat16* tA = tiles;                  // + buf * 2*BM*BK
    __hip_bfloat16* tB = tiles + BM * BK;        // + buf * 2*BM*BK

    const int tid  = threadIdx.x;
    const int wave = tid >> 6;
    const int lane = tid & 63;
    const int wm   = wave & 1;            // wave row (0..1)
    const int wn   = wave >> 1;           // wave col (0..1)
    const int g    = lane >> 4;           // quad  (0..3)
    const int m15  = lane & 15;

    if (tid < BM) { rs[tid] = 0.f; cs[tid] = 0.f; }

    // ---- staging addresses (computed once) ----
    // lane l covers LDS row rr = wave*32 + t*16 + (l>>2), lds chunk l&3;
    // swizzled source chunk = (l&3) ^ ((l>>3)&3)   [R6-validated, 0 conflicts]
    const int st_r0  = wave * 32 + (lane >> 2);            // t=0 row
    const int st_c   = (lane & 3) ^ ((lane >> 3) & 3);     // source chunk
    const __hip_bfloat16* gA0 = Z + (size_t)(bi * BM + st_r0) * HDIM + st_c * 8;
    const __hip_bfloat16* gA1 = gA0 + 16 * HDIM;           // t=1 rows
    const __hip_bfloat16* gB0 = Z + (size_t)(bj * BM + st_r0) * HDIM + st_c * 8;
    const __hip_bfloat16* gB1 = gB0 + 16 * HDIM;
    // wave-uniform LDS bases (lane scatter is +l*16B)
    __hip_bfloat16* lA0 = tA + (wave * 32) * BK;
    __hip_bfloat16* lA1 = tA + (wave * 32 + 16) * BK;
    __hip_bfloat16* lB0 = tB + (wave * 32) * BK;
    __hip_bfloat16* lB1 = tB + (wave * 32 + 16) * BK;

    // ---- fragment read addresses (all offsets immediates) ----
    const int sw = g ^ ((m15 >> 1) & 3);
    const __hip_bfloat16* rA = tA + (wm * 64 + m15) * BK + sw * 8;
    const __hip_bfloat16* rB = tB + (wn * 64 + m15) * BK + sw * 8;

    floatx4 acc[4][4] = {};

    // chunk ck -> buffer ck%3; global offset ck*BK folds to imm
    #define STAGE(ck)  do {                                                  \
        const int _o = ((ck) % 3) * 2 * BM * BK;                             \
        async_copy16(gA0 + (ck) * BK, lA0 + _o);                             \
        async_copy16(gA1 + (ck) * BK, lA1 + _o);                             \
        async_copy16(gB0 + (ck) * BK, lB0 + _o);                             \
        async_copy16(gB1 + (ck) * BK, lB1 + _o);                             \
    } while (0)

    STAGE(0);
    STAGE(1);

    #pragma unroll
    for (int s = 0; s < NCHUNK; ++s) {
        if (s + 2 < NCHUNK)      { STAGE(s + 2); WAIT_VM8(); }
        else if (s + 1 < NCHUNK) { WAIT_VM4(); }
        else                     { WAIT_VM0(); }
        RAW_BARRIER();   // chunk s landed in buffer s%3 (all waves)

        const int bo = (s % 3) * 2 * BM * BK;
        shortx8 af[4], bfr[4];
        #pragma unroll
        for (int f = 0; f < 4; ++f) {
            af[f]  = *(const shortx8*)(rA + bo + f * 16 * BK);
            bfr[f] = *(const shortx8*)(rB + bo + f * 16 * BK);
        }
        #pragma unroll
        for (int fm = 0; fm < 4; ++fm)
            #pragma unroll
            for (int fn = 0; fn < 4; ++fn)
                acc[fm][fn] = __builtin_amdgcn_mfma_f32_16x16x32_bf16(
                    af[fm], bfr[fn], acc[fm][fn], 0, 0, 0);

        WAIT_LGKM0();    // this buffer's ds_reads complete
        RAW_BARRIER();   // WAR: before buffer s%3 is restaged
    }
    #undef STAGE

    // ---- epilogue: e = exp2(acc) (== exp(sim/tau)), reduce rows & cols ----
    float rp[4][4] = {{0.f}};  // [fm][reg] partial row sums
    float cp[4]    = {0.f};    // [fn]      partial col sums

    if (!diag) {
        #pragma unroll
        for (int fm = 0; fm < 4; ++fm)
            #pragma unroll
            for (int fn = 0; fn < 4; ++fn) {
                const floatx4 a = acc[fm][fn];
                #pragma unroll
                for (int q = 0; q < 4; ++q) {
                    const float e = __builtin_amdgcn_exp2f(a[q]);
                    rp[fm][q] += e;
                    cp[fn]    += e;
                }
            }
    } else {
        #pragma unroll
        for (int fm = 0; fm < 4; ++fm)
            #pragma unroll
            for (int fn = 0; fn < 4; ++fn) {
                const floatx4 a = acc[fm][fn];
                const int cl = wn * 64 + fn * 16 + m15;
                #pragma unroll
                for (int q = 0; q < 4; ++q) {
                    const int rl = wm * 64 + fm * 16 + g * 4 + q;
                    float e = __builtin_amdgcn_exp2f(a[q]);
                    if (cl <= rl) e = 0.f;   // strictly-upper only
                    rp[fm][q] += e;
                    cp[fn]    += e;
                }
            }
    }

    // row sums: reduce across the 16 lanes of each DPP row (same rows of C)
    // via 4 row_shl DPP adds on the VALU pipe; total lands in m15==0 lanes.
    #pragma unroll
    for (int fm = 0; fm < 4; ++fm)
        #pragma unroll
        for (int q = 0; q < 4; ++q) {
            float v = rp[fm][q];
            DPP_ROW_SHL_ADD(v, 0x101);   // row_shl:1
            DPP_ROW_SHL_ADD(v, 0x102);   // row_shl:2
            DPP_ROW_SHL_ADD(v, 0x104);   // row_shl:4
            DPP_ROW_SHL_ADD(v, 0x108);   // row_shl:8
            rp[fm][q] = v;
        }
    if (m15 == 0) {
        #pragma unroll
        for (int fm = 0; fm < 4; ++fm)
            #pragma unroll
            for (int q = 0; q < 4; ++q)
                atomicAdd(&rs[wm * 64 + fm * 16 + g * 4 + q], rp[fm][q]);
    }

    // col sums: reduce across quads (xor 16/32 crosses DPP rows -> keep shfl)
    #pragma unroll
    for (int mask = 16; mask < 64; mask <<= 1)
        #pragma unroll
        for (int fn = 0; fn < 4; ++fn)
            cp[fn] += __shfl_xor(cp[fn], mask);
    if (g == 0) {
        #pragma unroll
        for (int fn = 0; fn < 4; ++fn)
            atomicAdd(&cs[wn * 64 + fn * 16 + m15], cp[fn]);
    }

    __syncthreads();
    if (tid < BM) {
        atomicAdd(&rowsum[(size_t)bi * BM + tid], rs[tid]);
        atomicAdd(&rowsum[(size_t)bj * BM + tid], cs[tid]);
    }
}

// ---------------------------------------------------------------------------
// Kernel 3: loss = mean( log(rowsum_i) - 2*pos_i ), 16 blocks + atomic.
// out[0] zeroed by normalize_kernel (stream-ordered).
// ---------------------------------------------------------------------------
__global__ __launch_bounds__(1024) void finalize_kernel(
    const float* __restrict__ rowsum, const float* __restrict__ pos,
    float* __restrict__ out)
{
    const int i = threadIdx.x + blockIdx.x * 1024;
    float s = logf(rowsum[i]) - 2.0f * pos[i];
    #pragma unroll
    for (int off = 32; off; off >>= 1) s += __shfl_down(s, off);
    __shared__ float sh[16];
    const int lt = threadIdx.x;
    if ((lt & 63) == 0) sh[lt >> 6] = s;
    __syncthreads();
    if (lt == 0) {
        float tot = 0.f;
        #pragma unroll
        for (int w = 0; w < 16; ++w) tot += sh[w];
        atomicAdd(out, tot / (float)N2);
    }
}

// ---------------------------------------------------------------------------
extern "C" void kernel_launch(void* const* d_in, const int* in_sizes, int n_in,
                              void* d_out, int out_size, void* d_ws, size_t ws_size,
                              hipStream_t stream)
{
    const float* x = (const float*)d_in[0];
    const float* y = (const float*)d_in[1];

    // workspace: Z bf16 [16384*256] (8 MB) | rowsum f32 [16384] | pos f32 [16384]
    __hip_bfloat16* Z = (__hip_bfloat16*)d_ws;
    float* rowsum = (float*)((char*)d_ws + (size_t)N2 * HDIM * sizeof(__hip_bfloat16));
    float* pos    = rowsum + N2;

    normalize_kernel<<<NROWS / 4, 256, 0, stream>>>(x, y, Z, pos, rowsum, (float*)d_out);
    simgemm_kernel<<<NBLK, 256, 0, stream>>>(Z, rowsum);
    finalize_kernel<<<N2 / 1024, 1024, 0, stream>>>(rowsum, pos, (float*)d_out);
}

// Round 10
// 157.250 us; speedup vs baseline: 2.0005x; 1.0109x over previous
//
#include <hip/hip_runtime.h>
#include <hip/hip_bf16.h>
#include <math.h>

// Problem constants (fixed by reference setup_inputs)
constexpr int NROWS = 8192;   // B
constexpr int HDIM  = 256;    // H (= K of the GEMM)
constexpr int N2    = 16384;  // 2*B rows of Z
constexpr int BM    = 128;    // tile M = tile N
constexpr int BK    = 32;     // K chunk staged per round (8 chunks)
constexpr int NCHUNK = HDIM / BK;     // 8
constexpr int NTILE = N2 / BM;        // 128 tile-rows
constexpr int NBLK  = NTILE * (NTILE + 1) / 2;  // 8256 upper-tri tiles

// sqrt(2 * log2(e)): Z pre-scaled so Zs_i.Zs_j = 2*log2(e)*cos and
// exp2(acc) == exp(sim/tau), tau = 0.5
constexpr float PRESCALE = 1.69864357f;

typedef __attribute__((ext_vector_type(4))) float floatx4;
typedef __attribute__((ext_vector_type(8))) short shortx8; // 8 bf16 = 4 VGPRs

__device__ __forceinline__ void async_copy16(const void* gptr, void* lptr) {
    __builtin_amdgcn_global_load_lds(
        (const __attribute__((address_space(1))) unsigned int*)gptr,
        (__attribute__((address_space(3))) unsigned int*)lptr, 16, 0, 0);
}

// s_waitcnt immediates (gfx9: vm[3:0], exp[6:4], lgkm[11:8], vm-hi[15:14])
#define WAIT_VM4()   __builtin_amdgcn_s_waitcnt(0x0F74)  // vmcnt(4)
#define WAIT_VM0()   __builtin_amdgcn_s_waitcnt(0x0F70)  // vmcnt(0)
#define MEMFENCE()   __asm__ __volatile__("" ::: "memory")
#define RAW_BARRIER() do { MEMFENCE(); __builtin_amdgcn_s_barrier(); MEMFENCE(); } while (0)

// DPP row_shl add: VALU pipe, not DS (R9: -18us vs ds_bpermute shuffles).
#define DPP_ROW_SHL_ADD(v, CTRL) do {                                        \
    union { float f; int i; } _u, _r; _u.f = (v);                            \
    _r.i = __builtin_amdgcn_update_dpp(0, _u.i, (CTRL), 0xF, 0xF, true);     \
    (v) += _r.f; } while (0)

// ---------------------------------------------------------------------------
// Kernel 1: wave-per-row L2-normalize -> bf16 Z (pre-scaled); pos = cos(x,y).
// Also zeroes rowsum and out (stream-ordered before consumers).
// ---------------------------------------------------------------------------
__global__ __launch_bounds__(256) void normalize_kernel(
    const float* __restrict__ x, const float* __restrict__ y,
    __hip_bfloat16* __restrict__ Z, float* __restrict__ pos,
    float* __restrict__ rowsum, float* __restrict__ out)
{
    const int wave = threadIdx.x >> 6, lane = threadIdx.x & 63;
    const int row  = blockIdx.x * 4 + wave;           // grid 2048 -> 8192 rows

    const float4 xv = ((const float4*)x)[row * 64 + lane];
    const float4 yv = ((const float4*)y)[row * 64 + lane];

    float sx  = xv.x*xv.x + xv.y*xv.y + xv.z*xv.z + xv.w*xv.w;
    float sy  = yv.x*yv.x + yv.y*yv.y + yv.z*yv.z + yv.w*yv.w;
    float sxy = xv.x*yv.x + xv.y*yv.y + xv.z*yv.z + xv.w*yv.w;
    #pragma unroll
    for (int m = 1; m < 64; m <<= 1) {
        sx  += __shfl_xor(sx,  m);
        sy  += __shfl_xor(sy,  m);
        sxy += __shfl_xor(sxy, m);
    }
    const float rxn = rsqrtf(sx), ryn = rsqrtf(sy);
    const float rx = rxn * PRESCALE, ry = ryn * PRESCALE;

    union { ushort4 u; __hip_bfloat16 h[4]; } zx, zy;
    zx.h[0] = __float2bfloat16(xv.x * rx); zx.h[1] = __float2bfloat16(xv.y * rx);
    zx.h[2] = __float2bfloat16(xv.z * rx); zx.h[3] = __float2bfloat16(xv.w * rx);
    zy.h[0] = __float2bfloat16(yv.x * ry); zy.h[1] = __float2bfloat16(yv.y * ry);
    zy.h[2] = __float2bfloat16(yv.z * ry); zy.h[3] = __float2bfloat16(yv.w * ry);
    ((ushort4*)Z)[row * 64 + lane]             = zx.u;
    ((ushort4*)Z)[(row + NROWS) * 64 + lane]   = zy.u;

    if (lane == 0) {
        const float p = sxy * rxn * ryn;
        pos[row]         = p;
        pos[row + NROWS] = p;
    }
    const int gt = blockIdx.x * 256 + threadIdx.x;
    if (gt < N2) rowsum[gt] = 0.f;
    if (gt == 0) out[0] = 0.f;
}

// ---------------------------------------------------------------------------
// Kernel 2: upper-triangle tiled Z·Z^T, fused exp2 + row/col sums.
// R9 structure (tbuf BK=32, XCD-locality mapping, DPP epilogue) with the
// K-loop reduced to ONE barrier per chunk, depth-1 prefetch, no lgkm drain:
//   body s: STAGE(s+1) -> buf (s+1)%3; WAIT_VM4 (own chunk-s loads landed);
//           BARRIER (all waves' chunk-s landed); ds_read buf s%3; MFMA.
// WAR safety without 2nd barrier: buf s%3 is next overwritten by STAGE at
// body s+2, which wave A reaches only after barrier s+1; wave B reaches
// barrier s+1 only after issuing body-s MFMAs, whose compiler-inserted
// lgkmcnt waits (in-order DS retirement) imply B's body-s ds_reads retired.
// NO device-scope fences (R5: collapses L2). No direct-from-global frags
// (R7: 16-segment scatter saturates TA).
// ---------------------------------------------------------------------------
__global__ __launch_bounds__(256, 3) void simgemm_kernel(
    const __hip_bfloat16* __restrict__ Z, float* __restrict__ rowsum)
{
    // ---- XCD-local block -> (bi,bj) mapping (bijection onto upper tri) ----
    const int b = blockIdx.x;
    const int k = b & 7;        // XCD under round-robin dispatch heuristic
    const int m = b >> 3;       // 0..1031 local rank within XCD
    int bi, bj;
    if (m < 136) {
        // diagonal group-pair k: 16x16 upper triangle, cum(t) = t*(33-t)/2
        int ti = (int)((33.0f - sqrtf(1089.0f - 8.0f * (float)m)) * 0.5f);
        if (m < ti * (33 - ti) / 2) ti--;
        else if (m >= (ti + 1) * (32 - ti) / 2) ti++;
        const int tj = ti + (m - ti * (33 - ti) / 2);
        bi = k * 16 + ti;
        bj = k * 16 + tj;
    } else {
        const int m2 = m - 136;          // 0..895
        const int hh = m2 >> 7;          // 0..6  (which of my 7 halves)
        const int r  = m2 & 127;         // 0..127 within half (8x16 tiles)
        const int h  = hh * 8 + k;       // 0..55 global half index
        const int q  = h >> 1;           // 0..27 off-diag group pair
        const int sub = h & 1;
        // pair q -> (gi,gj), gi<gj, cum(gi) = gi*(15-gi)/2
        int gi = 0;
        #pragma unroll
        for (int t = 6; t > 0; --t)
            if (q >= t * (15 - t) / 2) { gi = t; break; }
        const int gj = gi + 1 + (q - gi * (15 - gi) / 2);
        bi = gi * 16 + sub * 8 + (r >> 4);
        bj = gj * 16 + (r & 15);
    }
    const bool diag = (bi == bj);

    // LDS: 3 buffers x (tA 8KB + tB 8KB) = 48KB, + rs/cs 1KB
    __shared__ alignas(16) __hip_bfloat16 tiles[6 * BM * BK];  // 48 KB
    __shared__ float rs[BM];
    __shared__ float cs[BM];
    __hip_bfloat16* tA = tiles;                  // + buf * 2*BM*BK
    __hip_bfloat16* tB = tiles + BM * BK;        // + buf * 2*BM*BK

    const int tid  = threadIdx.x;
    const int wave = tid >> 6;
    const int lane = tid & 63;
    const int wm   = wave & 1;            // wave row (0..1)
    const int wn   = wave >> 1;           // wave col (0..1)
    const int g    = lane >> 4;           // quad  (0..3)
    const int m15  = lane & 15;

    if (tid < BM) { rs[tid] = 0.f; cs[tid] = 0.f; }

    // ---- staging addresses (computed once) ----
    // lane l covers LDS row rr = wave*32 + t*16 + (l>>2), lds chunk l&3;
    // swizzled source chunk = (l&3) ^ ((l>>3)&3)   [R6-validated, 0 conflicts]
    const int st_r0  = wave * 32 + (lane >> 2);            // t=0 row
    const int st_c   = (lane & 3) ^ ((lane >> 3) & 3);     // source chunk
    const __hip_bfloat16* gA0 = Z + (size_t)(bi * BM + st_r0) * HDIM + st_c * 8;
    const __hip_bfloat16* gA1 = gA0 + 16 * HDIM;           // t=1 rows
    const __hip_bfloat16* gB0 = Z + (size_t)(bj * BM + st_r0) * HDIM + st_c * 8;
    const __hip_bfloat16* gB1 = gB0 + 16 * HDIM;
    // wave-uniform LDS bases (lane scatter is +l*16B)
    __hip_bfloat16* lA0 = tA + (wave * 32) * BK;
    __hip_bfloat16* lA1 = tA + (wave * 32 + 16) * BK;
    __hip_bfloat16* lB0 = tB + (wave * 32) * BK;
    __hip_bfloat16* lB1 = tB + (wave * 32 + 16) * BK;

    // ---- fragment read addresses (all offsets immediates) ----
    const int sw = g ^ ((m15 >> 1) & 3);
    const __hip_bfloat16* rA = tA + (wm * 64 + m15) * BK + sw * 8;
    const __hip_bfloat16* rB = tB + (wn * 64 + m15) * BK + sw * 8;

    floatx4 acc[4][4] = {};

    // chunk ck -> buffer ck%3; global offset ck*BK folds to imm
    #define STAGE(ck)  do {                                                  \
        const int _o = ((ck) % 3) * 2 * BM * BK;                             \
        async_copy16(gA0 + (ck) * BK, lA0 + _o);                             \
        async_copy16(gA1 + (ck) * BK, lA1 + _o);                             \
        async_copy16(gB0 + (ck) * BK, lB0 + _o);                             \
        async_copy16(gB1 + (ck) * BK, lB1 + _o);                             \
    } while (0)

    STAGE(0);   // prologue

    #pragma unroll
    for (int s = 0; s < NCHUNK; ++s) {
        if (s + 1 < NCHUNK) { STAGE(s + 1); WAIT_VM4(); }
        else                { WAIT_VM0(); }
        RAW_BARRIER();   // all waves' chunk-s loads landed in buf s%3

        const int bo = (s % 3) * 2 * BM * BK;
        shortx8 af[4], bfr[4];
        #pragma unroll
        for (int f = 0; f < 4; ++f) {
            af[f]  = *(const shortx8*)(rA + bo + f * 16 * BK);
            bfr[f] = *(const shortx8*)(rB + bo + f * 16 * BK);
        }
        #pragma unroll
        for (int fm = 0; fm < 4; ++fm)
            #pragma unroll
            for (int fn = 0; fn < 4; ++fn)
                acc[fm][fn] = __builtin_amdgcn_mfma_f32_16x16x32_bf16(
                    af[fm], bfr[fn], acc[fm][fn], 0, 0, 0);
        // no 2nd barrier / lgkm drain: see WAR-safety argument above
    }
    #undef STAGE

    // ---- epilogue: e = exp2(acc) (== exp(sim/tau)), reduce rows & cols ----
    float rp[4][4] = {{0.f}};  // [fm][reg] partial row sums
    float cp[4]    = {0.f};    // [fn]      partial col sums

    if (!diag) {
        #pragma unroll
        for (int fm = 0; fm < 4; ++fm)
            #pragma unroll
            for (int fn = 0; fn < 4; ++fn) {
                const floatx4 a = acc[fm][fn];
                #pragma unroll
                for (int q = 0; q < 4; ++q) {
                    const float e = __builtin_amdgcn_exp2f(a[q]);
                    rp[fm][q] += e;
                    cp[fn]    += e;
                }
            }
    } else {
        #pragma unroll
        for (int fm = 0; fm < 4; ++fm)
            #pragma unroll
            for (int fn = 0; fn < 4; ++fn) {
                const floatx4 a = acc[fm][fn];
                const int cl = wn * 64 + fn * 16 + m15;
                #pragma unroll
                for (int q = 0; q < 4; ++q) {
                    const int rl = wm * 64 + fm * 16 + g * 4 + q;
                    float e = __builtin_amdgcn_exp2f(a[q]);
                    if (cl <= rl) e = 0.f;   // strictly-upper only
                    rp[fm][q] += e;
                    cp[fn]    += e;
                }
            }
    }

    // row sums: 16-lane DPP reduction (VALU pipe); total lands in m15==0
    #pragma unroll
    for (int fm = 0; fm < 4; ++fm)
        #pragma unroll
        for (int q = 0; q < 4; ++q) {
            float v = rp[fm][q];
            DPP_ROW_SHL_ADD(v, 0x101);   // row_shl:1
            DPP_ROW_SHL_ADD(v, 0x102);   // row_shl:2
            DPP_ROW_SHL_ADD(v, 0x104);   // row_shl:4
            DPP_ROW_SHL_ADD(v, 0x108);   // row_shl:8
            rp[fm][q] = v;
        }
    if (m15 == 0) {
        #pragma unroll
        for (int fm = 0; fm < 4; ++fm)
            #pragma unroll
            for (int q = 0; q < 4; ++q)
                atomicAdd(&rs[wm * 64 + fm * 16 + g * 4 + q], rp[fm][q]);
    }

    // col sums: reduce across quads (xor 16/32 crosses DPP rows -> keep shfl)
    #pragma unroll
    for (int mask = 16; mask < 64; mask <<= 1)
        #pragma unroll
        for (int fn = 0; fn < 4; ++fn)
            cp[fn] += __shfl_xor(cp[fn], mask);
    if (g == 0) {
        #pragma unroll
        for (int fn = 0; fn < 4; ++fn)
            atomicAdd(&cs[wn * 64 + fn * 16 + m15], cp[fn]);
    }

    __syncthreads();
    if (tid < BM) {
        atomicAdd(&rowsum[(size_t)bi * BM + tid], rs[tid]);
        atomicAdd(&rowsum[(size_t)bj * BM + tid], cs[tid]);
    }
}

// ---------------------------------------------------------------------------
// Kernel 3: loss = mean( log(rowsum_i) - 2*pos_i ), 16 blocks + atomic.
// out[0] zeroed by normalize_kernel (stream-ordered).
// ---------------------------------------------------------------------------
__global__ __launch_bounds__(1024) void finalize_kernel(
    const float* __restrict__ rowsum, const float* __restrict__ pos,
    float* __restrict__ out)
{
    const int i = threadIdx.x + blockIdx.x * 1024;
    float s = logf(rowsum[i]) - 2.0f * pos[i];
    #pragma unroll
    for (int off = 32; off; off >>= 1) s += __shfl_down(s, off);
    __shared__ float sh[16];
    const int lt = threadIdx.x;
    if ((lt & 63) == 0) sh[lt >> 6] = s;
    __syncthreads();
    if (lt == 0) {
        float tot = 0.f;
        #pragma unroll
        for (int w = 0; w < 16; ++w) tot += sh[w];
        atomicAdd(out, tot / (float)N2);
    }
}

// ---------------------------------------------------------------------------
extern "C" void kernel_launch(void* const* d_in, const int* in_sizes, int n_in,
                              void* d_out, int out_size, void* d_ws, size_t ws_size,
                              hipStream_t stream)
{
    const float* x = (const float*)d_in[0];
    const float* y = (const float*)d_in[1];

    // workspace: Z bf16 [16384*256] (8 MB) | rowsum f32 [16384] | pos f32 [16384]
    __hip_bfloat16* Z = (__hip_bfloat16*)d_ws;
    float* rowsum = (float*)((char*)d_ws + (size_t)N2 * HDIM * sizeof(__hip_bfloat16));
    float* pos    = rowsum + N2;

    normalize_kernel<<<NROWS / 4, 256, 0, stream>>>(x, y, Z, pos, rowsum, (float*)d_out);
    simgemm_kernel<<<NBLK, 256, 0, stream>>>(Z, rowsum);
    finalize_kernel<<<N2 / 1024, 1024, 0, stream>>>(rowsum, pos, (float*)d_out);
}